// Round 6
// baseline (2547.116 us; speedup 1.0000x reference)
//
#include <hip/hip_runtime.h>
#include <hip/hip_bf16.h>
#include <math.h>

#define HID 128
#define SCB 256

typedef short short8 __attribute__((ext_vector_type(8)));
typedef float f32x4 __attribute__((ext_vector_type(4)));

// ---------------- init: zero counts + stats + counters ----------------
__global__ void init_kernel(int* counts, int n, float* stats, int* counters) {
    int i = blockIdx.x * blockDim.x + threadIdx.x;
    if (i < n) counts[i] = 0;
    if (i < 3 * 2 * HID) stats[i] = 0.f;
    if (i < 3) counters[i] = 0;
}

__global__ void count_kernel(const int* __restrict__ dst, int* __restrict__ counts, int ne) {
    int i = blockIdx.x * blockDim.x + threadIdx.x;
    if (i < ne) atomicAdd(&counts[dst[i]], 1);
}

__global__ __launch_bounds__(SCB) void scan_blocks_kernel(const int* __restrict__ counts,
                                                          int* __restrict__ offsets,
                                                          int* __restrict__ partials, int n) {
    __shared__ int tmp[SCB];
    int t = threadIdx.x;
    int gid = blockIdx.x * SCB + t;
    int v = (gid < n) ? counts[gid] : 0;
    tmp[t] = v;
    __syncthreads();
    for (int off = 1; off < SCB; off <<= 1) {
        int u = 0;
        if (t >= off) u = tmp[t - off];
        __syncthreads();
        if (t >= off) tmp[t] += u;
        __syncthreads();
    }
    if (gid < n) offsets[gid] = tmp[t] - v;
    if (t == SCB - 1) partials[blockIdx.x] = tmp[t];
}

__global__ __launch_bounds__(1024) void scan_partials_kernel(int* __restrict__ partials, int nb) {
    __shared__ int tmp[1024];
    int t = threadIdx.x;
    int v = (t < nb) ? partials[t] : 0;
    tmp[t] = v;
    __syncthreads();
    for (int off = 1; off < 1024; off <<= 1) {
        int u = 0;
        if (t >= off) u = tmp[t - off];
        __syncthreads();
        if (t >= off) tmp[t] += u;
        __syncthreads();
    }
    if (t < nb) partials[t] = tmp[t] - v;
}

__global__ __launch_bounds__(SCB) void scan_add_kernel(int* __restrict__ offsets,
                                                       const int* __restrict__ partials,
                                                       int* __restrict__ cursor, int n) {
    int gid = blockIdx.x * SCB + threadIdx.x;
    if (gid < n) {
        int v = offsets[gid] + partials[blockIdx.x];
        offsets[gid] = v;
        cursor[gid] = v;
    }
}

__global__ void fill_kernel(const int* __restrict__ src, const int* __restrict__ dst,
                            int* __restrict__ cursor, int* __restrict__ esrc, int ne) {
    int i = blockIdx.x * blockDim.x + threadIdx.x;
    if (i < ne) {
        int d = dst[i];
        int pos = atomicAdd(&cursor[d], 1);
        esrc[pos] = src[i];
    }
}

// ---------------- pad x to [N][K0pad] fp32 ----------------
__global__ void pad_x_kernel(const float* __restrict__ x, float* __restrict__ xp,
                             int N, int K, int Kpad) {
    int i = blockIdx.x * blockDim.x + threadIdx.x;
    if (i >= N * Kpad) return;
    int row = i / Kpad;
    int c = i - row * Kpad;
    xp[i] = (c < K) ? x[(size_t)row * K + c] : 0.f;
}

// ---------------- all 3 layers' weights -> bf16 hi/lo B^T in one dispatch ----------------
__global__ void convert_w_all_kernel(const float* __restrict__ Wn0, const float* __restrict__ Wr0,
                                     const float* __restrict__ Wn1, const float* __restrict__ Wr1,
                                     const float* __restrict__ Wn2, const float* __restrict__ Wr2,
                                     unsigned short* __restrict__ B0h, unsigned short* __restrict__ B0l,
                                     unsigned short* __restrict__ B1h, unsigned short* __restrict__ B1l,
                                     unsigned short* __restrict__ B2h, unsigned short* __restrict__ B2l,
                                     int K0, int K0pad) {
    int i = blockIdx.x * blockDim.x + threadIdx.x;
    int n0 = 256 * K0pad, n1 = 256 * HID;
    const float *Wn, *Wr;
    unsigned short *bh, *bl;
    int K, Kpad, idx;
    if (i < n0) { Wn = Wn0; Wr = Wr0; bh = B0h; bl = B0l; K = K0; Kpad = K0pad; idx = i; }
    else if (i < n0 + n1) { Wn = Wn1; Wr = Wr1; bh = B1h; bl = B1l; K = HID; Kpad = HID; idx = i - n0; }
    else if (i < n0 + 2 * n1) { Wn = Wn2; Wr = Wr2; bh = B2h; bl = B2l; K = HID; Kpad = HID; idx = i - n0 - n1; }
    else return;
    int ch = idx / Kpad;
    int k = idx - ch * Kpad;
    float v = 0.f;
    if (k < K) v = (ch < 128) ? Wn[k * 128 + ch] : Wr[k * 128 + (ch - 128)];
    __hip_bfloat16 h = __float2bfloat16(v);
    float hf = __bfloat162float(h);
    __hip_bfloat16 l = __float2bfloat16(v - hf);
    bh[idx] = *(unsigned short*)&h;
    bl[idx] = *(unsigned short*)&l;
}

// ---------------- LDS-free MFMA dual GEMM with fused BN+ReLU+bf16-split on A ----------------
// A = fp32 [N][Kpad] (Z of previous layer, or padded x). apply_bn: y=relu(a*sc+sh) else y=a.
__global__ __launch_bounds__(256) void gemm_kernel(
    const float* __restrict__ A, int Kpad, int apply_bn,
    const float* __restrict__ scale, const float* __restrict__ shift,
    const unsigned short* __restrict__ BTh, const unsigned short* __restrict__ BTl,
    float* __restrict__ U, float* __restrict__ V, int N) {
    int tid = threadIdx.x;
    int lane = tid & 63;
    int w = tid >> 6;
    int q = lane >> 4;
    int m = lane & 15;
    int n0 = blockIdx.x * 64;

    f32x4 acc[4][4];
#pragma unroll
    for (int r = 0; r < 4; r++)
#pragma unroll
        for (int c = 0; c < 4; c++) acc[r][c] = (f32x4){0.f, 0.f, 0.f, 0.f};

    size_t abase[4], bbase[4];
#pragma unroll
    for (int r = 0; r < 4; r++) {
        int row = n0 + 16 * r + m;
        if (row >= N) row = N - 1;
        abase[r] = (size_t)row * Kpad;
    }
#pragma unroll
    for (int c = 0; c < 4; c++) bbase[c] = (size_t)(64 * w + 16 * c + m) * Kpad;

    int ksteps = Kpad >> 5;
    for (int ks = 0; ks < ksteps; ks++) {
        int ko = ks * 32 + q * 8;
        float scv[8], shv[8];
        if (apply_bn) {
            float4 s0 = *(const float4*)&scale[ko];
            float4 s1 = *(const float4*)&scale[ko + 4];
            float4 h0 = *(const float4*)&shift[ko];
            float4 h1 = *(const float4*)&shift[ko + 4];
            scv[0]=s0.x; scv[1]=s0.y; scv[2]=s0.z; scv[3]=s0.w;
            scv[4]=s1.x; scv[5]=s1.y; scv[6]=s1.z; scv[7]=s1.w;
            shv[0]=h0.x; shv[1]=h0.y; shv[2]=h0.z; shv[3]=h0.w;
            shv[4]=h1.x; shv[5]=h1.y; shv[6]=h1.z; shv[7]=h1.w;
        }
        short8 ah[4], al[4], bh[4], bl[4];
#pragma unroll
        for (int r = 0; r < 4; r++) {
            float4 z0 = *(const float4*)(A + abase[r] + ko);
            float4 z1 = *(const float4*)(A + abase[r] + ko + 4);
            float y[8] = {z0.x, z0.y, z0.z, z0.w, z1.x, z1.y, z1.z, z1.w};
            if (apply_bn) {
#pragma unroll
                for (int j = 0; j < 8; j++) y[j] = fmaxf(fmaf(y[j], scv[j], shv[j]), 0.f);
            }
#pragma unroll
            for (int j = 0; j < 8; j++) {
                __hip_bfloat16 h = __float2bfloat16(y[j]);
                float hf = __bfloat162float(h);
                __hip_bfloat16 lo = __float2bfloat16(y[j] - hf);
                ah[r][j] = *(short*)&h;
                al[r][j] = *(short*)&lo;
            }
        }
#pragma unroll
        for (int c = 0; c < 4; c++) {
            bh[c] = __builtin_bit_cast(short8, *(const uint4*)(BTh + bbase[c] + ko));
            bl[c] = __builtin_bit_cast(short8, *(const uint4*)(BTl + bbase[c] + ko));
        }
#pragma unroll
        for (int r = 0; r < 4; r++)
#pragma unroll
            for (int c = 0; c < 4; c++) {
                acc[r][c] = __builtin_amdgcn_mfma_f32_16x16x32_bf16(ah[r], bh[c], acc[r][c], 0, 0, 0);
                acc[r][c] = __builtin_amdgcn_mfma_f32_16x16x32_bf16(ah[r], bl[c], acc[r][c], 0, 0, 0);
                acc[r][c] = __builtin_amdgcn_mfma_f32_16x16x32_bf16(al[r], bh[c], acc[r][c], 0, 0, 0);
            }
    }
    // C/D: col = lane&15, row = quad*4 + reg  [m89-verified]
    float* Out = (w < 2) ? U : V;
    int colbase = (w & 1) * 64;
#pragma unroll
    for (int r = 0; r < 4; r++)
#pragma unroll
        for (int c = 0; c < 4; c++) {
            int col = colbase + 16 * c + m;
#pragma unroll
            for (int i = 0; i < 4; i++) {
                int row = n0 + 16 * r + 4 * q + i;
                if (row < N) Out[(size_t)row * HID + col] = acc[r][c][i];
            }
        }
}

// ---------------- agg + fused BN stats + last-block finalize ----------------
// Z[n] = mean_{e->n} U[src_e] + V[n] + bias. 8 nodes/block, 32 lanes x float4 per node.
__global__ __launch_bounds__(256) void agg_kernel(const float* __restrict__ U,
                                                  const float* __restrict__ V,
                                                  const float* __restrict__ bias,
                                                  const int* __restrict__ counts,
                                                  const int* __restrict__ offsets,
                                                  const int* __restrict__ esrc,
                                                  float* __restrict__ Z, int N,
                                                  float* __restrict__ sums,
                                                  float* __restrict__ sumsq,
                                                  int* __restrict__ counter,
                                                  const float* __restrict__ g,
                                                  const float* __restrict__ be,
                                                  float* __restrict__ scale,
                                                  float* __restrict__ shift) {
    int tid = threadIdx.x;
    int grp = tid >> 5;
    int l32 = tid & 31;
    int n = blockIdx.x * 8 + grp;
    f32x4 zv = {0.f, 0.f, 0.f, 0.f};
    if (n < N) {
        int deg = counts[n];
        int st = offsets[n];
        const f32x4* U4 = (const f32x4*)U;
        f32x4 a0 = {0,0,0,0}, a1 = {0,0,0,0}, a2 = {0,0,0,0}, a3 = {0,0,0,0};
        f32x4 a4 = {0,0,0,0}, a5 = {0,0,0,0}, a6 = {0,0,0,0}, a7 = {0,0,0,0};
        int i = 0;
        for (; i + 7 < deg; i += 8) {
            int s0 = esrc[st + i + 0], s1 = esrc[st + i + 1];
            int s2 = esrc[st + i + 2], s3 = esrc[st + i + 3];
            int s4 = esrc[st + i + 4], s5 = esrc[st + i + 5];
            int s6 = esrc[st + i + 6], s7 = esrc[st + i + 7];
            a0 += U4[(size_t)s0 * 32 + l32];
            a1 += U4[(size_t)s1 * 32 + l32];
            a2 += U4[(size_t)s2 * 32 + l32];
            a3 += U4[(size_t)s3 * 32 + l32];
            a4 += U4[(size_t)s4 * 32 + l32];
            a5 += U4[(size_t)s5 * 32 + l32];
            a6 += U4[(size_t)s6 * 32 + l32];
            a7 += U4[(size_t)s7 * 32 + l32];
        }
        for (; i + 3 < deg; i += 4) {
            int s0 = esrc[st + i + 0], s1 = esrc[st + i + 1];
            int s2 = esrc[st + i + 2], s3 = esrc[st + i + 3];
            a0 += U4[(size_t)s0 * 32 + l32];
            a1 += U4[(size_t)s1 * 32 + l32];
            a2 += U4[(size_t)s2 * 32 + l32];
            a3 += U4[(size_t)s3 * 32 + l32];
        }
        for (; i < deg; i++) a0 += U4[(size_t)esrc[st + i] * 32 + l32];
        f32x4 acc = ((a0 + a1) + (a2 + a3)) + ((a4 + a5) + (a6 + a7));
        float d = (float)(deg > 1 ? deg : 1);
        f32x4 vv = ((const f32x4*)V)[(size_t)n * 32 + l32];
        f32x4 bb = ((const f32x4*)bias)[l32];
        zv = acc / d + vv + bb;
        ((f32x4*)Z)[(size_t)n * 32 + l32] = zv;
    }
    // block-local channel stats over the 8 rows
    __shared__ f32x4 bs[256], bq[256];
    bs[tid] = zv;
    bq[tid] = zv * zv;
    __syncthreads();
#pragma unroll
    for (int off = 4; off > 0; off >>= 1) {
        if (grp < off) {
            bs[tid] += bs[tid + off * 32];
            bq[tid] += bq[tid + off * 32];
        }
        __syncthreads();
    }
    if (grp == 0) {
#pragma unroll
        for (int j = 0; j < 4; j++) {
            atomicAdd(&sums[4 * l32 + j], bs[tid][j]);
            atomicAdd(&sumsq[4 * l32 + j], bq[tid][j]);
        }
    }
    __threadfence();
    __shared__ int isLast;
    if (tid == 0) {
        int old = atomicAdd(counter, 1);
        isLast = (old == (int)gridDim.x - 1);
    }
    __syncthreads();
    if (isLast) {
        __threadfence();
        if (tid < HID) {
            float S = __hip_atomic_load(&sums[tid], __ATOMIC_RELAXED, __HIP_MEMORY_SCOPE_AGENT);
            float Q = __hip_atomic_load(&sumsq[tid], __ATOMIC_RELAXED, __HIP_MEMORY_SCOPE_AGENT);
            float mu = S / (float)N;
            float var = Q / (float)N - mu * mu;
            if (var < 0.f) var = 0.f;
            float rs = 1.f / sqrtf(var + 1e-5f);
            float sc = g[tid] * rs;
            scale[tid] = sc;
            shift[tid] = be[tid] - mu * sc;
        }
    }
}

// ---------------- fused BN+ReLU + segmented mean pool + MLP head ----------------
__global__ __launch_bounds__(128) void pool_head_kernel(const float* __restrict__ Z,
                                                        const float* __restrict__ scale,
                                                        const float* __restrict__ shift,
                                                        const int* __restrict__ batch,
                                                        const float* __restrict__ Wh1,
                                                        const float* __restrict__ bh1,
                                                        const float* __restrict__ Wh2,
                                                        const float* __restrict__ bh2,
                                                        float* __restrict__ out, int N) {
    int gph = blockIdx.x;
    __shared__ int bounds[2];
    __shared__ float p[128];
    int t = threadIdx.x;
    if (t < 2) {
        int target = gph + t;
        int lo = 0, hi = N;
        while (lo < hi) {
            int mid = (lo + hi) >> 1;
            if (batch[mid] < target) lo = mid + 1;
            else hi = mid;
        }
        bounds[t] = lo;
    }
    __syncthreads();
    int start = bounds[0], end = bounds[1];
    float sc = scale[t], sh = shift[t];
    float s = 0.f;
    for (int n = start; n < end; n++)
        s += fmaxf(fmaf(Z[(size_t)n * HID + t], sc, sh), 0.f);
    p[t] = s / fmaxf((float)(end - start), 1.f);
    __syncthreads();
    if (t < 64) {
        float acc = bh1[t];
        for (int k = 0; k < 128; k++) acc = fmaf(p[k], Wh1[k * 64 + t], acc);
        acc = fmaxf(acc, 0.f);
        float prod = acc * Wh2[t];
        for (int off = 32; off > 0; off >>= 1) prod += __shfl_down(prod, off);
        if (t == 0) out[gph] = prod + bh2[0];
    }
}

extern "C" void kernel_launch(void* const* d_in, const int* in_sizes, int n_in,
                              void* d_out, int out_size, void* d_ws, size_t ws_size,
                              hipStream_t stream) {
    const float* x = (const float*)d_in[0];
    const int* ei = (const int*)d_in[1];
    const int* batch = (const int*)d_in[2];
    const float* Wn[3] = {(const float*)d_in[3], (const float*)d_in[8], (const float*)d_in[13]};
    const float* bb[3] = {(const float*)d_in[4], (const float*)d_in[9], (const float*)d_in[14]};
    const float* Wr[3] = {(const float*)d_in[5], (const float*)d_in[10], (const float*)d_in[15]};
    const float* gg[3] = {(const float*)d_in[6], (const float*)d_in[11], (const float*)d_in[16]};
    const float* be[3] = {(const float*)d_in[7], (const float*)d_in[12], (const float*)d_in[17]};
    const float* Wh1 = (const float*)d_in[18];
    const float* bh1 = (const float*)d_in[19];
    const float* Wh2 = (const float*)d_in[20];
    const float* bh2 = (const float*)d_in[21];
    float* out = (float*)d_out;

    const int N = in_sizes[2];       // 50000
    const int NE = in_sizes[1] / 2;  // 800000
    const int NG = out_size;         // 1000
    const int K0 = in_sizes[0] / N;  // 78
    const int K0pad = ((K0 + 31) / 32) * 32;  // 96

    const int* src = ei;
    const int* dst = ei + NE;

    char* w = (char*)d_ws;
    auto alloc = [&](size_t bytes) -> void* {
        void* p = (void*)w;
        w += (bytes + 255) & ~(size_t)255;
        return p;
    };
    float* bufU = (float*)alloc((size_t)N * HID * 4);
    float* bufV = (float*)alloc((size_t)N * HID * 4);
    float* bufZ = (float*)alloc((size_t)N * HID * 4);
    float* xp = (float*)alloc((size_t)N * K0pad * 4);
    unsigned short* BTh[3];
    unsigned short* BTl[3];
    BTh[0] = (unsigned short*)alloc((size_t)256 * K0pad * 2);
    BTl[0] = (unsigned short*)alloc((size_t)256 * K0pad * 2);
    BTh[1] = (unsigned short*)alloc((size_t)256 * HID * 2);
    BTl[1] = (unsigned short*)alloc((size_t)256 * HID * 2);
    BTh[2] = (unsigned short*)alloc((size_t)256 * HID * 2);
    BTl[2] = (unsigned short*)alloc((size_t)256 * HID * 2);
    int* counts = (int*)alloc((size_t)N * 4);
    int* offsets = (int*)alloc((size_t)(N + 1) * 4);
    int* cursor = (int*)alloc((size_t)N * 4);
    int* esrc = (int*)alloc((size_t)NE * 4);
    int* partials = (int*)alloc(1024 * 4);
    float* stats = (float*)alloc(3 * 2 * HID * 4);  // [layer][sum|sumsq][128]
    int* counters = (int*)alloc(3 * 4);
    float* scaleL = (float*)alloc(3 * HID * 4);
    float* shiftL = (float*)alloc(3 * HID * 4);
    (void)ws_size;
    (void)n_in;

    // ---- CSR + init ----
    int nscb = (N + SCB - 1) / SCB;
    init_kernel<<<(N + 255) / 256, 256, 0, stream>>>(counts, N, stats, counters);
    count_kernel<<<(NE + 255) / 256, 256, 0, stream>>>(dst, counts, NE);
    scan_blocks_kernel<<<nscb, SCB, 0, stream>>>(counts, offsets, partials, N);
    scan_partials_kernel<<<1, 1024, 0, stream>>>(partials, nscb);
    scan_add_kernel<<<nscb, SCB, 0, stream>>>(offsets, partials, cursor, N);
    fill_kernel<<<(NE + 255) / 256, 256, 0, stream>>>(src, dst, cursor, esrc, NE);

    // ---- input pad + weight converts (one dispatch) ----
    pad_x_kernel<<<((size_t)N * K0pad + 255) / 256, 256, 0, stream>>>(x, xp, N, K0, K0pad);
    int cw_total = 256 * K0pad + 2 * 256 * HID;
    convert_w_all_kernel<<<(cw_total + 255) / 256, 256, 0, stream>>>(
        Wn[0], Wr[0], Wn[1], Wr[1], Wn[2], Wr[2],
        BTh[0], BTl[0], BTh[1], BTl[1], BTh[2], BTl[2], K0, K0pad);

    // ---- 3 fused SAGE layers: gemm(+prev BN) -> agg(+stats+finalize) ----
    int gblocks = (N + 63) / 64;
    int ablocks = (N + 7) / 8;
    for (int l = 0; l < 3; l++) {
        const float* Ain = (l == 0) ? xp : bufZ;
        int Kpad = (l == 0) ? K0pad : HID;
        const float* psc = (l == 0) ? (const float*)nullptr : scaleL + (l - 1) * HID;
        const float* psh = (l == 0) ? (const float*)nullptr : shiftL + (l - 1) * HID;
        gemm_kernel<<<gblocks, 256, 0, stream>>>(Ain, Kpad, (l > 0) ? 1 : 0, psc, psh,
                                                 BTh[l], BTl[l], bufU, bufV, N);
        agg_kernel<<<ablocks, 256, 0, stream>>>(bufU, bufV, bb[l], counts, offsets, esrc,
                                                bufZ, N,
                                                stats + l * 2 * HID, stats + l * 2 * HID + HID,
                                                counters + l, gg[l], be[l],
                                                scaleL + l * HID, shiftL + l * HID);
    }

    // ---- fused BN+ReLU+pool+head ----
    pool_head_kernel<<<NG, 128, 0, stream>>>(bufZ, scaleL + 2 * HID, shiftL + 2 * HID,
                                             batch, Wh1, bh1, Wh2, bh2, out, N);
}

// Round 7
// 666.725 us; speedup vs baseline: 3.8203x; 3.8203x over previous
//
#include <hip/hip_runtime.h>
#include <hip/hip_bf16.h>
#include <math.h>

#define HID 128
#define SCB 256

typedef short short8 __attribute__((ext_vector_type(8)));
typedef float f32x4 __attribute__((ext_vector_type(4)));

// ---------------- init: zero counts + stats ----------------
__global__ void init_kernel(int* counts, int n, double* stats) {
    int i = blockIdx.x * blockDim.x + threadIdx.x;
    if (i < n) counts[i] = 0;
    if (i < 3 * 2 * HID) stats[i] = 0.0;
}

__global__ void count_kernel(const int* __restrict__ dst, int* __restrict__ counts, int ne) {
    int i = blockIdx.x * blockDim.x + threadIdx.x;
    if (i < ne) atomicAdd(&counts[dst[i]], 1);
}

__global__ __launch_bounds__(SCB) void scan_blocks_kernel(const int* __restrict__ counts,
                                                          int* __restrict__ offsets,
                                                          int* __restrict__ partials, int n) {
    __shared__ int tmp[SCB];
    int t = threadIdx.x;
    int gid = blockIdx.x * SCB + t;
    int v = (gid < n) ? counts[gid] : 0;
    tmp[t] = v;
    __syncthreads();
    for (int off = 1; off < SCB; off <<= 1) {
        int u = 0;
        if (t >= off) u = tmp[t - off];
        __syncthreads();
        if (t >= off) tmp[t] += u;
        __syncthreads();
    }
    if (gid < n) offsets[gid] = tmp[t] - v;
    if (t == SCB - 1) partials[blockIdx.x] = tmp[t];
}

__global__ __launch_bounds__(1024) void scan_partials_kernel(int* __restrict__ partials, int nb) {
    __shared__ int tmp[1024];
    int t = threadIdx.x;
    int v = (t < nb) ? partials[t] : 0;
    tmp[t] = v;
    __syncthreads();
    for (int off = 1; off < 1024; off <<= 1) {
        int u = 0;
        if (t >= off) u = tmp[t - off];
        __syncthreads();
        if (t >= off) tmp[t] += u;
        __syncthreads();
    }
    if (t < nb) partials[t] = tmp[t] - v;
}

__global__ __launch_bounds__(SCB) void scan_add_kernel(int* __restrict__ offsets,
                                                       const int* __restrict__ partials,
                                                       int* __restrict__ cursor, int n) {
    int gid = blockIdx.x * SCB + threadIdx.x;
    if (gid < n) {
        int v = offsets[gid] + partials[blockIdx.x];
        offsets[gid] = v;
        cursor[gid] = v;
    }
}

__global__ void fill_kernel(const int* __restrict__ src, const int* __restrict__ dst,
                            int* __restrict__ cursor, int* __restrict__ esrc, int ne) {
    int i = blockIdx.x * blockDim.x + threadIdx.x;
    if (i < ne) {
        int d = dst[i];
        int pos = atomicAdd(&cursor[d], 1);
        esrc[pos] = src[i];
    }
}

// ---------------- pad x to [N][K0pad] fp32 ----------------
__global__ void pad_x_kernel(const float* __restrict__ x, float* __restrict__ xp,
                             int N, int K, int Kpad) {
    int i = blockIdx.x * blockDim.x + threadIdx.x;
    if (i >= N * Kpad) return;
    int row = i / Kpad;
    int c = i - row * Kpad;
    xp[i] = (c < K) ? x[(size_t)row * K + c] : 0.f;
}

// ---------------- all 3 layers' weights -> bf16 hi/lo B^T in one dispatch ----------------
__global__ void convert_w_all_kernel(const float* __restrict__ Wn0, const float* __restrict__ Wr0,
                                     const float* __restrict__ Wn1, const float* __restrict__ Wr1,
                                     const float* __restrict__ Wn2, const float* __restrict__ Wr2,
                                     unsigned short* __restrict__ B0h, unsigned short* __restrict__ B0l,
                                     unsigned short* __restrict__ B1h, unsigned short* __restrict__ B1l,
                                     unsigned short* __restrict__ B2h, unsigned short* __restrict__ B2l,
                                     int K0, int K0pad) {
    int i = blockIdx.x * blockDim.x + threadIdx.x;
    int n0 = 256 * K0pad, n1 = 256 * HID;
    const float *Wn, *Wr;
    unsigned short *bh, *bl;
    int K, Kpad, idx;
    if (i < n0) { Wn = Wn0; Wr = Wr0; bh = B0h; bl = B0l; K = K0; Kpad = K0pad; idx = i; }
    else if (i < n0 + n1) { Wn = Wn1; Wr = Wr1; bh = B1h; bl = B1l; K = HID; Kpad = HID; idx = i - n0; }
    else if (i < n0 + 2 * n1) { Wn = Wn2; Wr = Wr2; bh = B2h; bl = B2l; K = HID; Kpad = HID; idx = i - n0 - n1; }
    else return;
    int ch = idx / Kpad;
    int k = idx - ch * Kpad;
    float v = 0.f;
    if (k < K) v = (ch < 128) ? Wn[k * 128 + ch] : Wr[k * 128 + (ch - 128)];
    __hip_bfloat16 h = __float2bfloat16(v);
    float hf = __bfloat162float(h);
    __hip_bfloat16 l = __float2bfloat16(v - hf);
    bh[idx] = *(unsigned short*)&h;
    bl[idx] = *(unsigned short*)&l;
}

// ---------------- LDS-free MFMA dual GEMM with fused BN+ReLU+bf16-split on A ----------------
__global__ __launch_bounds__(256) void gemm_kernel(
    const float* __restrict__ A, int Kpad, int apply_bn,
    const float* __restrict__ scale, const float* __restrict__ shift,
    const unsigned short* __restrict__ BTh, const unsigned short* __restrict__ BTl,
    float* __restrict__ U, float* __restrict__ V, int N) {
    int tid = threadIdx.x;
    int lane = tid & 63;
    int w = tid >> 6;
    int q = lane >> 4;
    int m = lane & 15;
    int n0 = blockIdx.x * 64;

    f32x4 acc[4][4];
#pragma unroll
    for (int r = 0; r < 4; r++)
#pragma unroll
        for (int c = 0; c < 4; c++) acc[r][c] = (f32x4){0.f, 0.f, 0.f, 0.f};

    size_t abase[4], bbase[4];
#pragma unroll
    for (int r = 0; r < 4; r++) {
        int row = n0 + 16 * r + m;
        if (row >= N) row = N - 1;
        abase[r] = (size_t)row * Kpad;
    }
#pragma unroll
    for (int c = 0; c < 4; c++) bbase[c] = (size_t)(64 * w + 16 * c + m) * Kpad;

    int ksteps = Kpad >> 5;
    for (int ks = 0; ks < ksteps; ks++) {
        int ko = ks * 32 + q * 8;
        float scv[8], shv[8];
        if (apply_bn) {
            float4 s0 = *(const float4*)&scale[ko];
            float4 s1 = *(const float4*)&scale[ko + 4];
            float4 h0 = *(const float4*)&shift[ko];
            float4 h1 = *(const float4*)&shift[ko + 4];
            scv[0]=s0.x; scv[1]=s0.y; scv[2]=s0.z; scv[3]=s0.w;
            scv[4]=s1.x; scv[5]=s1.y; scv[6]=s1.z; scv[7]=s1.w;
            shv[0]=h0.x; shv[1]=h0.y; shv[2]=h0.z; shv[3]=h0.w;
            shv[4]=h1.x; shv[5]=h1.y; shv[6]=h1.z; shv[7]=h1.w;
        }
        short8 ah[4], al[4], bh[4], bl[4];
#pragma unroll
        for (int r = 0; r < 4; r++) {
            float4 z0 = *(const float4*)(A + abase[r] + ko);
            float4 z1 = *(const float4*)(A + abase[r] + ko + 4);
            float y[8] = {z0.x, z0.y, z0.z, z0.w, z1.x, z1.y, z1.z, z1.w};
            if (apply_bn) {
#pragma unroll
                for (int j = 0; j < 8; j++) y[j] = fmaxf(fmaf(y[j], scv[j], shv[j]), 0.f);
            }
#pragma unroll
            for (int j = 0; j < 8; j++) {
                __hip_bfloat16 h = __float2bfloat16(y[j]);
                float hf = __bfloat162float(h);
                __hip_bfloat16 lo = __float2bfloat16(y[j] - hf);
                ah[r][j] = *(short*)&h;
                al[r][j] = *(short*)&lo;
            }
        }
#pragma unroll
        for (int c = 0; c < 4; c++) {
            bh[c] = __builtin_bit_cast(short8, *(const uint4*)(BTh + bbase[c] + ko));
            bl[c] = __builtin_bit_cast(short8, *(const uint4*)(BTl + bbase[c] + ko));
        }
#pragma unroll
        for (int r = 0; r < 4; r++)
#pragma unroll
            for (int c = 0; c < 4; c++) {
                acc[r][c] = __builtin_amdgcn_mfma_f32_16x16x32_bf16(ah[r], bh[c], acc[r][c], 0, 0, 0);
                acc[r][c] = __builtin_amdgcn_mfma_f32_16x16x32_bf16(ah[r], bl[c], acc[r][c], 0, 0, 0);
                acc[r][c] = __builtin_amdgcn_mfma_f32_16x16x32_bf16(al[r], bh[c], acc[r][c], 0, 0, 0);
            }
    }
    // C/D: col = lane&15, row = quad*4 + reg  [m89-verified]
    float* Out = (w < 2) ? U : V;
    int colbase = (w & 1) * 64;
#pragma unroll
    for (int r = 0; r < 4; r++)
#pragma unroll
        for (int c = 0; c < 4; c++) {
            int col = colbase + 16 * c + m;
#pragma unroll
            for (int i = 0; i < 4; i++) {
                int row = n0 + 16 * r + 4 * q + i;
                if (row < N) Out[(size_t)row * HID + col] = acc[r][c][i];
            }
        }
}

// ---------------- pure aggregation: Z[n] = mean_{e->n} U[src_e] + V[n] + bias ----------------
// NO fences, NO cross-block games (R6 post-mortem: device fences in hot kernels poison L2).
__global__ __launch_bounds__(256) void agg_kernel(const float* __restrict__ U,
                                                  const float* __restrict__ V,
                                                  const float* __restrict__ bias,
                                                  const int* __restrict__ counts,
                                                  const int* __restrict__ offsets,
                                                  const int* __restrict__ esrc,
                                                  float* __restrict__ Z, int N) {
    int grp = threadIdx.x >> 5;
    int l32 = threadIdx.x & 31;
    int n = blockIdx.x * 8 + grp;
    if (n >= N) return;
    int deg = counts[n];
    int st = offsets[n];
    const f32x4* U4 = (const f32x4*)U;
    f32x4 a0 = {0,0,0,0}, a1 = {0,0,0,0}, a2 = {0,0,0,0}, a3 = {0,0,0,0};
    f32x4 a4 = {0,0,0,0}, a5 = {0,0,0,0}, a6 = {0,0,0,0}, a7 = {0,0,0,0};
    int i = 0;
    for (; i + 7 < deg; i += 8) {
        int s0 = esrc[st + i + 0], s1 = esrc[st + i + 1];
        int s2 = esrc[st + i + 2], s3 = esrc[st + i + 3];
        int s4 = esrc[st + i + 4], s5 = esrc[st + i + 5];
        int s6 = esrc[st + i + 6], s7 = esrc[st + i + 7];
        a0 += U4[(size_t)s0 * 32 + l32];
        a1 += U4[(size_t)s1 * 32 + l32];
        a2 += U4[(size_t)s2 * 32 + l32];
        a3 += U4[(size_t)s3 * 32 + l32];
        a4 += U4[(size_t)s4 * 32 + l32];
        a5 += U4[(size_t)s5 * 32 + l32];
        a6 += U4[(size_t)s6 * 32 + l32];
        a7 += U4[(size_t)s7 * 32 + l32];
    }
    for (; i + 3 < deg; i += 4) {
        int s0 = esrc[st + i + 0], s1 = esrc[st + i + 1];
        int s2 = esrc[st + i + 2], s3 = esrc[st + i + 3];
        a0 += U4[(size_t)s0 * 32 + l32];
        a1 += U4[(size_t)s1 * 32 + l32];
        a2 += U4[(size_t)s2 * 32 + l32];
        a3 += U4[(size_t)s3 * 32 + l32];
    }
    for (; i < deg; i++) a0 += U4[(size_t)esrc[st + i] * 32 + l32];
    f32x4 acc = ((a0 + a1) + (a2 + a3)) + ((a4 + a5) + (a6 + a7));
    float d = (float)(deg > 1 ? deg : 1);
    f32x4 vv = ((const f32x4*)V)[(size_t)n * 32 + l32];
    f32x4 bb = ((const f32x4*)bias)[l32];
    ((f32x4*)Z)[(size_t)n * 32 + l32] = acc / d + vv + bb;
}

// ---------------- BN stats (separate, cheap) ----------------
__global__ __launch_bounds__(256) void stats_kernel(const float* __restrict__ Z,
                                                    double* __restrict__ sums,
                                                    double* __restrict__ sumsq, int N) {
    int t = threadIdx.x;
    int cq = t & 31;
    int rg = t >> 5;
    const f32x4* Z4 = (const f32x4*)Z;
    f32x4 s = {0,0,0,0}, q = {0,0,0,0};
    for (int n = blockIdx.x * 8 + rg; n < N; n += gridDim.x * 8) {
        f32x4 z = Z4[(size_t)n * 32 + cq];
        s += z;
        q += z * z;
    }
    __shared__ f32x4 bs[256], bq[256];
    bs[t] = s;
    bq[t] = q;
    __syncthreads();
    for (int off = 4; off > 0; off >>= 1) {
        if (rg < off) {
            bs[t] += bs[t + off * 32];
            bq[t] += bq[t + off * 32];
        }
        __syncthreads();
    }
    if (t < 32) {
        f32x4 S = bs[t], Q = bq[t];
#pragma unroll
        for (int j = 0; j < 4; j++) {
            atomicAdd(&sums[4 * t + j], (double)S[j]);
            atomicAdd(&sumsq[4 * t + j], (double)Q[j]);
        }
    }
}

__global__ __launch_bounds__(128) void bn_finalize_kernel(const double* __restrict__ sums,
                                                          const double* __restrict__ sumsq,
                                                          const float* __restrict__ g,
                                                          const float* __restrict__ be,
                                                          float* __restrict__ scale,
                                                          float* __restrict__ shift, int N) {
    int c = threadIdx.x;
    double mu = sums[c] / (double)N;
    double var = sumsq[c] / (double)N - mu * mu;
    if (var < 0.0) var = 0.0;
    float rs = (float)(1.0 / sqrt(var + 1e-5));
    float sc = g[c] * rs;
    scale[c] = sc;
    shift[c] = be[c] - (float)mu * sc;
}

// ---------------- fused BN+ReLU + segmented mean pool + MLP head ----------------
__global__ __launch_bounds__(128) void pool_head_kernel(const float* __restrict__ Z,
                                                        const float* __restrict__ scale,
                                                        const float* __restrict__ shift,
                                                        const int* __restrict__ batch,
                                                        const float* __restrict__ Wh1,
                                                        const float* __restrict__ bh1,
                                                        const float* __restrict__ Wh2,
                                                        const float* __restrict__ bh2,
                                                        float* __restrict__ out, int N) {
    int gph = blockIdx.x;
    __shared__ int bounds[2];
    __shared__ float p[128];
    int t = threadIdx.x;
    if (t < 2) {
        int target = gph + t;
        int lo = 0, hi = N;
        while (lo < hi) {
            int mid = (lo + hi) >> 1;
            if (batch[mid] < target) lo = mid + 1;
            else hi = mid;
        }
        bounds[t] = lo;
    }
    __syncthreads();
    int start = bounds[0], end = bounds[1];
    float sc = scale[t], sh = shift[t];
    float s = 0.f;
    for (int n = start; n < end; n++)
        s += fmaxf(fmaf(Z[(size_t)n * HID + t], sc, sh), 0.f);
    p[t] = s / fmaxf((float)(end - start), 1.f);
    __syncthreads();
    if (t < 64) {
        float acc = bh1[t];
        for (int k = 0; k < 128; k++) acc = fmaf(p[k], Wh1[k * 64 + t], acc);
        acc = fmaxf(acc, 0.f);
        float prod = acc * Wh2[t];
        for (int off = 32; off > 0; off >>= 1) prod += __shfl_down(prod, off);
        if (t == 0) out[gph] = prod + bh2[0];
    }
}

extern "C" void kernel_launch(void* const* d_in, const int* in_sizes, int n_in,
                              void* d_out, int out_size, void* d_ws, size_t ws_size,
                              hipStream_t stream) {
    const float* x = (const float*)d_in[0];
    const int* ei = (const int*)d_in[1];
    const int* batch = (const int*)d_in[2];
    const float* Wn[3] = {(const float*)d_in[3], (const float*)d_in[8], (const float*)d_in[13]};
    const float* bb[3] = {(const float*)d_in[4], (const float*)d_in[9], (const float*)d_in[14]};
    const float* Wr[3] = {(const float*)d_in[5], (const float*)d_in[10], (const float*)d_in[15]};
    const float* gg[3] = {(const float*)d_in[6], (const float*)d_in[11], (const float*)d_in[16]};
    const float* be[3] = {(const float*)d_in[7], (const float*)d_in[12], (const float*)d_in[17]};
    const float* Wh1 = (const float*)d_in[18];
    const float* bh1 = (const float*)d_in[19];
    const float* Wh2 = (const float*)d_in[20];
    const float* bh2 = (const float*)d_in[21];
    float* out = (float*)d_out;

    const int N = in_sizes[2];       // 50000
    const int NE = in_sizes[1] / 2;  // 800000
    const int NG = out_size;         // 1000
    const int K0 = in_sizes[0] / N;  // 78
    const int K0pad = ((K0 + 31) / 32) * 32;  // 96

    const int* src = ei;
    const int* dst = ei + NE;

    char* w = (char*)d_ws;
    auto alloc = [&](size_t bytes) -> void* {
        void* p = (void*)w;
        w += (bytes + 255) & ~(size_t)255;
        return p;
    };
    float* bufU = (float*)alloc((size_t)N * HID * 4);
    float* bufV = (float*)alloc((size_t)N * HID * 4);
    float* bufZ = (float*)alloc((size_t)N * HID * 4);
    float* xp = (float*)alloc((size_t)N * K0pad * 4);
    unsigned short* BTh[3];
    unsigned short* BTl[3];
    BTh[0] = (unsigned short*)alloc((size_t)256 * K0pad * 2);
    BTl[0] = (unsigned short*)alloc((size_t)256 * K0pad * 2);
    BTh[1] = (unsigned short*)alloc((size_t)256 * HID * 2);
    BTl[1] = (unsigned short*)alloc((size_t)256 * HID * 2);
    BTh[2] = (unsigned short*)alloc((size_t)256 * HID * 2);
    BTl[2] = (unsigned short*)alloc((size_t)256 * HID * 2);
    int* counts = (int*)alloc((size_t)N * 4);
    int* offsets = (int*)alloc((size_t)(N + 1) * 4);
    int* cursor = (int*)alloc((size_t)N * 4);
    int* esrc = (int*)alloc((size_t)NE * 4);
    int* partials = (int*)alloc(1024 * 4);
    double* stats = (double*)alloc(3 * 2 * HID * 8);  // [layer][sum|sumsq][128]
    float* scaleL = (float*)alloc(3 * HID * 4);
    float* shiftL = (float*)alloc(3 * HID * 4);
    (void)ws_size;
    (void)n_in;

    // ---- CSR + init ----
    int nscb = (N + SCB - 1) / SCB;
    init_kernel<<<(N + 255) / 256, 256, 0, stream>>>(counts, N, stats);
    count_kernel<<<(NE + 255) / 256, 256, 0, stream>>>(dst, counts, NE);
    scan_blocks_kernel<<<nscb, SCB, 0, stream>>>(counts, offsets, partials, N);
    scan_partials_kernel<<<1, 1024, 0, stream>>>(partials, nscb);
    scan_add_kernel<<<nscb, SCB, 0, stream>>>(offsets, partials, cursor, N);
    fill_kernel<<<(NE + 255) / 256, 256, 0, stream>>>(src, dst, cursor, esrc, NE);

    // ---- input pad + weight converts ----
    pad_x_kernel<<<((size_t)N * K0pad + 255) / 256, 256, 0, stream>>>(x, xp, N, K0, K0pad);
    int cw_total = 256 * K0pad + 2 * 256 * HID;
    convert_w_all_kernel<<<(cw_total + 255) / 256, 256, 0, stream>>>(
        Wn[0], Wr[0], Wn[1], Wr[1], Wn[2], Wr[2],
        BTh[0], BTl[0], BTh[1], BTl[1], BTh[2], BTl[2], K0, K0pad);

    // ---- 3 SAGE layers: gemm(+prev BN) -> agg -> stats -> finalize ----
    int gblocks = (N + 63) / 64;
    int ablocks = (N + 7) / 8;
    for (int l = 0; l < 3; l++) {
        const float* Ain = (l == 0) ? xp : bufZ;
        int Kpad = (l == 0) ? K0pad : HID;
        const float* psc = (l == 0) ? (const float*)nullptr : scaleL + (l - 1) * HID;
        const float* psh = (l == 0) ? (const float*)nullptr : shiftL + (l - 1) * HID;
        double* sums = stats + l * 2 * HID;
        double* sumsq = sums + HID;
        gemm_kernel<<<gblocks, 256, 0, stream>>>(Ain, Kpad, (l > 0) ? 1 : 0, psc, psh,
                                                 BTh[l], BTl[l], bufU, bufV, N);
        agg_kernel<<<ablocks, 256, 0, stream>>>(bufU, bufV, bb[l], counts, offsets, esrc, bufZ, N);
        stats_kernel<<<512, 256, 0, stream>>>(bufZ, sums, sumsq, N);
        bn_finalize_kernel<<<1, 128, 0, stream>>>(sums, sumsq, gg[l], be[l],
                                                  scaleL + l * HID, shiftL + l * HID, N);
    }

    // ---- fused BN+ReLU+pool+head ----
    pool_head_kernel<<<NG, 128, 0, stream>>>(bufZ, scaleL + 2 * HID, shiftL + 2 * HID,
                                             batch, Wh1, bh1, Wh2, bh2, out, N);
}